// Round 8
// baseline (448.325 us; speedup 1.0000x reference)
//
#include <hip/hip_runtime.h>

#define DM 256

typedef __attribute__((ext_vector_type(8))) short bf16x8;
typedef __attribute__((ext_vector_type(4))) float f32x4;
typedef __attribute__((ext_vector_type(4))) unsigned short us16x4;
typedef __attribute__((ext_vector_type(8))) unsigned short us16x8;
typedef unsigned short us16;

__device__ __forceinline__ unsigned short f2bf(float f) {
  unsigned int u = __float_as_uint(f);
  u += 0x7fffu + ((u >> 16) & 1u);          // round-to-nearest-even
  return (unsigned short)(u >> 16);
}
__device__ __forceinline__ float bf2f(unsigned short s) {
  return __uint_as_float(((unsigned int)s) << 16);
}

__device__ __forceinline__ void gload16(const void* g, void* l) {
  __builtin_amdgcn_global_load_lds(
      (const __attribute__((address_space(1))) void*)g,
      (__attribute__((address_space(3))) void*)l, 16, 0, 0);
}

// ---------------- fused QKV GEMM (one dispatch, grid.z = 0:Q, 1:K, 2:V)
// 128x256 tile, 8 waves (2x4), BK=32, fp32 A reg-staged+converted, B via
// global_load_lds. z>0 writes the KV-interleaved layout:
//   K col c -> elem (c>>2)*8 + (c&3); V col c -> (c>>2)*8 + 4 + (c&3)
__global__ __launch_bounds__(512) void qkv_gemm(
    const float* __restrict__ Fa, const float* __restrict__ Fb,
    const us16* __restrict__ W_all, us16* __restrict__ Qbf,
    us16* __restrict__ KVbf, int NA, int NB)
{
  const int z = blockIdx.z;
  const float* A = (z == 0) ? Fa : Fb;
  const int Mreal = (z == 0) ? NA : NB;
  const int Mp = (Mreal + 127) & ~127;
  const us16* W = W_all + (size_t)z * 256 * 256;
  us16* Cb = (z == 0) ? Qbf : KVbf;
  const int ldc = (z == 0) ? 256 : 512;

  __shared__ us16 As[128 * 32];
  __shared__ us16 Bs[256 * 32];
  const int tid = threadIdx.x;
  const int w = tid >> 6, l = tid & 63;
  const int wr = w >> 2, wc = w & 3;          // wave grid 2 x 4
  const int rowBase = blockIdx.x * 128;
  if (rowBase >= Mp) return;
  const int ar = tid >> 2, ac = (tid & 3) * 8;
  f32x4 acc[4][4] = {};

  for (int k0 = 0; k0 < 256; k0 += 32) {
#pragma unroll
    for (int j = 0; j < 2; ++j) {
      const int r0 = (w * 2 + j) * 16;
      gload16(W + (size_t)(r0 + (l >> 2)) * 256 + k0 + (l & 3) * 8, &Bs[r0 * 32]);
    }
    {
      const int grow = rowBase + ar;
      bf16x8 av = (bf16x8){0, 0, 0, 0, 0, 0, 0, 0};
      if (grow < Mreal) {
        const float4 x = *(const float4*)(A + (size_t)grow * 256 + k0 + ac);
        const float4 y = *(const float4*)(A + (size_t)grow * 256 + k0 + ac + 4);
        av[0] = (short)f2bf(x.x); av[1] = (short)f2bf(x.y);
        av[2] = (short)f2bf(x.z); av[3] = (short)f2bf(x.w);
        av[4] = (short)f2bf(y.x); av[5] = (short)f2bf(y.y);
        av[6] = (short)f2bf(y.z); av[7] = (short)f2bf(y.w);
      }
      *(bf16x8*)&As[ar * 32 + ac] = av;
    }
    __syncthreads();
    bf16x8 af[4], bfr[4];
#pragma unroll
    for (int m = 0; m < 4; ++m)
      af[m] = *(const bf16x8*)&As[(wr * 64 + m * 16 + (l & 15)) * 32 + (l >> 4) * 8];
#pragma unroll
    for (int n = 0; n < 4; ++n)
      bfr[n] = *(const bf16x8*)&Bs[(wc * 64 + n * 16 + (l & 15)) * 32 + (l >> 4) * 8];
#pragma unroll
    for (int m = 0; m < 4; ++m)
#pragma unroll
      for (int n = 0; n < 4; ++n)
        acc[m][n] = __builtin_amdgcn_mfma_f32_16x16x32_bf16(af[m], bfr[n], acc[m][n], 0, 0, 0);
    __syncthreads();
  }

  // epilogue: C/D layout col=lane&15, row=(lane>>4)*4+j  [m89-verified]
  const int er = (l >> 4) * 4;
  const int ec = l & 15;
  const int vofs = (z == 2) ? 4 : 0;
#pragma unroll
  for (int m = 0; m < 4; ++m)
#pragma unroll
    for (int n = 0; n < 4; ++n)
#pragma unroll
      for (int j = 0; j < 4; ++j) {
        const int grow = rowBase + wr * 64 + m * 16 + er + j;
        const int c = wc * 64 + n * 16 + ec;          // local col 0..255
        const int col = (z == 0) ? c : ((c >> 2) * 8 + (c & 3) + vofs);
        Cb[(size_t)grow * ldc + col] = f2bf(acc[m][n][j]);
      }
}

// ---------------- proj GEMM: C = A(bf16) @ Wp^T + R, fp32 out, row-guarded
__global__ __launch_bounds__(512) void proj_gemm(
    const us16* __restrict__ A, const us16* __restrict__ W,
    float* __restrict__ Cf, const float* __restrict__ R, int Mreal)
{
  __shared__ us16 As[128 * 32];
  __shared__ us16 Bs[256 * 32];
  const int tid = threadIdx.x;
  const int w = tid >> 6, l = tid & 63;
  const int wr = w >> 2, wc = w & 3;
  const int rowBase = blockIdx.x * 128;
  const int ar = tid >> 2, ac = (tid & 3) * 8;
  f32x4 acc[4][4] = {};

  for (int k0 = 0; k0 < 256; k0 += 32) {
#pragma unroll
    for (int j = 0; j < 2; ++j) {
      const int r0 = (w * 2 + j) * 16;
      gload16(W + (size_t)(r0 + (l >> 2)) * 256 + k0 + (l & 3) * 8, &Bs[r0 * 32]);
    }
    *(bf16x8*)&As[ar * 32 + ac] =
        *(const bf16x8*)(A + (size_t)(rowBase + ar) * 256 + k0 + ac);
    __syncthreads();
    bf16x8 af[4], bfr[4];
#pragma unroll
    for (int m = 0; m < 4; ++m)
      af[m] = *(const bf16x8*)&As[(wr * 64 + m * 16 + (l & 15)) * 32 + (l >> 4) * 8];
#pragma unroll
    for (int n = 0; n < 4; ++n)
      bfr[n] = *(const bf16x8*)&Bs[(wc * 64 + n * 16 + (l & 15)) * 32 + (l >> 4) * 8];
#pragma unroll
    for (int m = 0; m < 4; ++m)
#pragma unroll
      for (int n = 0; n < 4; ++n)
        acc[m][n] = __builtin_amdgcn_mfma_f32_16x16x32_bf16(af[m], bfr[n], acc[m][n], 0, 0, 0);
    __syncthreads();
  }

  const int er = (l >> 4) * 4;
  const int ec = l & 15;
#pragma unroll
  for (int m = 0; m < 4; ++m)
#pragma unroll
    for (int n = 0; n < 4; ++n)
#pragma unroll
      for (int j = 0; j < 4; ++j) {
        const int grow = rowBase + wr * 64 + m * 16 + er + j;
        if (grow < Mreal) {
          const size_t off = (size_t)grow * 256 + wc * 64 + n * 16 + ec;
          Cf[off] = acc[m][n][j] + R[off];
        }
      }
}

// ---------------- all 4 weight matrices -> one bf16 [1024 x 256] buffer
__global__ void cvt_weights(const float* __restrict__ Wq, const float* __restrict__ Wk,
                            const float* __restrict__ Wv, const float* __restrict__ Wp,
                            us16* __restrict__ out)
{
  const int g = blockIdx.x * 256 + threadIdx.x;      // 32768 threads
  const size_t e = (size_t)g * 8;
  const int sel = (int)(e >> 16);
  const float* src = (sel == 0) ? Wq : (sel == 1) ? Wk : (sel == 2) ? Wv : Wp;
  const size_t loc = e & 65535;
  const float4 x = *(const float4*)(src + loc);
  const float4 y = *(const float4*)(src + loc + 4);
  bf16x8 o;
  o[0] = (short)f2bf(x.x); o[1] = (short)f2bf(x.y);
  o[2] = (short)f2bf(x.z); o[3] = (short)f2bf(x.w);
  o[4] = (short)f2bf(y.x); o[5] = (short)f2bf(y.y);
  o[6] = (short)f2bf(y.z); o[7] = (short)f2bf(y.w);
  *(bf16x8*)(out + e) = o;
}

// ---------------- CSR build ----------------
__global__ void hist_kernel(const int* __restrict__ a_idx, int* __restrict__ counts, int E)
{
  const int e = blockIdx.x * 256 + threadIdx.x;
  if (e < E) atomicAdd(&counts[a_idx[e]], 1);
}

__global__ __launch_bounds__(256) void scan_offs(const int* __restrict__ counts,
    int* __restrict__ offs, int* __restrict__ cursor, int* __restrict__ total, int n)
{
  __shared__ int buf[256];
  __shared__ int sbase;
  const int t = threadIdx.x;
  const int i = blockIdx.x * 256 + t;
  const int v = (i < n) ? counts[i] : 0;
  buf[t] = v;
  __syncthreads();
#pragma unroll
  for (int off = 1; off < 256; off <<= 1) {
    const int x = (t >= off) ? buf[t - off] : 0;
    __syncthreads();
    buf[t] += x;
    __syncthreads();
  }
  const int incl = buf[t];
  if (t == 255) sbase = atomicAdd(total, incl);
  __syncthreads();
  if (i < n) {
    const int excl = sbase + incl - v;
    offs[i] = excl;
    cursor[i] = excl;
  }
}

__global__ void scatter_kernel(const int* __restrict__ a_idx, const int* __restrict__ b_idx,
    int* __restrict__ cursor, int* __restrict__ bel, int E)
{
  const int e = blockIdx.x * 256 + threadIdx.x;
  if (e < E) bel[atomicAdd(&cursor[a_idx[e]], 1)] = b_idx[e];
}

// ---------------- edge attention: ONE WAVE per node, 4-deep pipeline.
// KV interleaved: lane l = head (l>>3), group l; ONE dwordx4 per edge gives
// [k0..k3, v0..v3] for its 4 dims. 3-shuffle reduce over the 8-lane head.
#define ATTN_STEP(S, J)                                        \
  if ((J) < cnt) {                                             \
    float p = q0 * bf2f(S[0]);                                 \
    p = fmaf(q1, bf2f(S[1]), p);                               \
    p = fmaf(q2, bf2f(S[2]), p);                               \
    p = fmaf(q3, bf2f(S[3]), p);                               \
    p += __shfl_xor(p, 1, 64);                                 \
    p += __shfl_xor(p, 2, 64);                                 \
    p += __shfl_xor(p, 4, 64);                                 \
    const float ex = __expf(p * scale);                        \
    ssum += ex;                                                \
    acc0 = fmaf(ex, bf2f(S[4]), acc0);                         \
    acc1 = fmaf(ex, bf2f(S[5]), acc1);                         \
    acc2 = fmaf(ex, bf2f(S[6]), acc2);                         \
    acc3 = fmaf(ex, bf2f(S[7]), acc3);                         \
  }

#define ATTN_LOAD(S, IDX)                                      \
  S = *(const us16x8*)(KVb + (size_t)bel[start + (IDX)] * 512 + l * 8);

__global__ __launch_bounds__(256) void edge_attn(
    const us16* __restrict__ Qb, const us16* __restrict__ KVb,
    const int* __restrict__ offs, const int* __restrict__ counts,
    const int* __restrict__ bel, us16* __restrict__ outb, int NA)
{
  const int a = blockIdx.x * 4 + (threadIdx.x >> 6);
  if (a >= NA) return;
  const int l = threadIdx.x & 63;
  const float scale = 0.17677669529663687f;   // 1/sqrt(32)

  const us16x4 q4 = *(const us16x4*)(Qb + (size_t)a * 256 + l * 4);
  const float q0 = bf2f(q4[0]), q1 = bf2f(q4[1]), q2 = bf2f(q4[2]), q3 = bf2f(q4[3]);

  const int start = offs[a];
  const int cnt = counts[a];
  float acc0 = 0.f, acc1 = 0.f, acc2 = 0.f, acc3 = 0.f, ssum = 0.f;

  if (cnt > 0) {
    const int last = cnt - 1;
    us16x8 sa, sb, sc, sd;
    ATTN_LOAD(sa, 0)
    ATTN_LOAD(sb, min(1, last))
    ATTN_LOAD(sc, min(2, last))
    ATTN_LOAD(sd, min(3, last))
    for (int i = 0; i < cnt; i += 4) {
      us16x8 na, nb, nc, nd;
      ATTN_LOAD(na, min(i + 4, last))
      ATTN_LOAD(nb, min(i + 5, last))
      ATTN_LOAD(nc, min(i + 6, last))
      ATTN_LOAD(nd, min(i + 7, last))
      ATTN_STEP(sa, i + 0)
      ATTN_STEP(sb, i + 1)
      ATTN_STEP(sc, i + 2)
      ATTN_STEP(sd, i + 3)
      sa = na; sb = nb; sc = nc; sd = nd;
    }
  }

  const float inv = (cnt > 0) ? 1.f / ssum : 0.f;
  us16x4 o;
  o[0] = f2bf(acc0 * inv); o[1] = f2bf(acc1 * inv);
  o[2] = f2bf(acc2 * inv); o[3] = f2bf(acc3 * inv);
  *(us16x4*)(outb + (size_t)a * 256 + l * 4) = o;
}

extern "C" void kernel_launch(void* const* d_in, const int* in_sizes, int n_in,
                              void* d_out, int out_size, void* d_ws, size_t ws_size,
                              hipStream_t stream)
{
  const float* Fa    = (const float*)d_in[0];
  const float* Fb    = (const float*)d_in[1];
  const int*   a_idx = (const int*)d_in[2];
  const int*   b_idx = (const int*)d_in[3];
  const float* Wq    = (const float*)d_in[4];
  const float* Wk    = (const float*)d_in[5];
  const float* Wv    = (const float*)d_in[6];
  const float* Wproj = (const float*)d_in[7];
  float* out = (float*)d_out;

  const int NA = in_sizes[0] / DM;
  const int NB = in_sizes[1] / DM;
  const int E  = in_sizes[2];
  const int MAp = (NA + 127) & ~127;
  const int NBp = (NB + 127) & ~127;
  const int MXp = (MAp > NBp) ? MAp : NBp;

  // workspace: Qbf | KVbf | ATbf | W_all | ints
  us16* Qbf   = (us16*)d_ws;                        // MAp*256
  us16* KVbf  = Qbf   + (size_t)MAp * 256;          // NBp*512 (interleaved KV)
  us16* ATbf  = KVbf  + (size_t)NBp * 512;          // MAp*256
  us16* W_all = ATbf  + (size_t)MAp * 256;          // 1024*256: [Wq;Wk;Wv;Wp]
  int* total  = (int*)(W_all + 1024 * 256);
  int* counts = total + 1;
  int* offs   = counts + NA;
  int* cursor = offs + NA;
  int* bel    = cursor + NA;

  hipMemsetAsync(total, 0, (size_t)(NA + 1) * sizeof(int), stream);

  cvt_weights<<<128, 256, 0, stream>>>(Wq, Wk, Wv, Wproj, W_all);

  // CSR build
  hist_kernel<<<(E + 255) / 256, 256, 0, stream>>>(a_idx, counts, E);
  scan_offs<<<(NA + 255) / 256, 256, 0, stream>>>(counts, offs, cursor, total, NA);
  scatter_kernel<<<(E + 255) / 256, 256, 0, stream>>>(a_idx, b_idx, cursor, bel, E);

  // fused Q/K/V projections (one dispatch, z = 0/1/2)
  qkv_gemm<<<dim3(MXp / 128, 1, 3), 512, 0, stream>>>(Fa, Fb, W_all, Qbf, KVbf, NA, NB);

  // attention: one wave per node, 4 nodes per block
  edge_attn<<<(NA + 3) / 4, 256, 0, stream>>>(Qbf, KVbf, offs, counts, bel, ATbf, NA);

  // output projection + residual (fp32 out, guarded)
  proj_gemm<<<dim3(MAp / 128, 1), 512, 0, stream>>>(ATbf, W_all + 768 * 256, out, Fa, NA);
}

// Round 10
// 438.190 us; speedup vs baseline: 1.0231x; 1.0231x over previous
//
#include <hip/hip_runtime.h>

#define DM 256

typedef __attribute__((ext_vector_type(8))) short bf16x8;
typedef __attribute__((ext_vector_type(4))) float f32x4;
typedef __attribute__((ext_vector_type(4))) unsigned short us16x4;
typedef __attribute__((ext_vector_type(8))) unsigned short us16x8;
typedef unsigned short us16;

__device__ __forceinline__ unsigned short f2bf(float f) {
  unsigned int u = __float_as_uint(f);
  u += 0x7fffu + ((u >> 16) & 1u);          // round-to-nearest-even
  return (unsigned short)(u >> 16);
}
__device__ __forceinline__ float bf2f(unsigned short s) {
  return __uint_as_float(((unsigned int)s) << 16);
}

__device__ __forceinline__ void gload16(const void* g, void* l) {
  __builtin_amdgcn_global_load_lds(
      (const __attribute__((address_space(1))) void*)g,
      (__attribute__((address_space(3))) void*)l, 16, 0, 0);
}

// ---------------- fused QKV GEMM (one dispatch, grid.z = 0:Q, 1:K, 2:V)
// 128x256 tile, 8 waves (2x4), BK=32, 2-PHASE double-buffered K-loop:
// issue next tile's A-reg loads + B global_load_lds BEFORE current MFMAs,
// ds_write A after MFMAs, ONE barrier per iter. z>0 writes KV-interleaved:
//   K col c -> elem (c>>2)*8 + (c&3); V col c -> (c>>2)*8 + 4 + (c&3)
__global__ __launch_bounds__(512) void qkv_gemm(
    const float* __restrict__ Fa, const float* __restrict__ Fb,
    const us16* __restrict__ W_all, us16* __restrict__ Qbf,
    us16* __restrict__ KVbf, int NA, int NB)
{
  const int z = blockIdx.z;
  const float* A = (z == 0) ? Fa : Fb;
  const int Mreal = (z == 0) ? NA : NB;
  const int Mp = (Mreal + 127) & ~127;
  const us16* W = W_all + (size_t)z * 256 * 256;
  us16* Cb = (z == 0) ? Qbf : KVbf;
  const int ldc = (z == 0) ? 256 : 512;

  __shared__ us16 As[2][128 * 32];
  __shared__ us16 Bs[2][256 * 32];
  const int tid = threadIdx.x;
  const int w = tid >> 6, l = tid & 63;
  const int wr = w >> 2, wc = w & 3;          // wave grid 2 x 4
  const int rowBase = blockIdx.x * 128;
  if (rowBase >= Mp) return;
  const int ar = tid >> 2, ac = (tid & 3) * 8;
  const int grow0 = rowBase + ar;
  const bool aval = grow0 < Mreal;
  const float* Ap = A + (size_t)grow0 * 256 + ac;
  f32x4 acc[4][4] = {};

  // prologue: stage k0=0 into buffer 0
  {
    float4 x = make_float4(0.f, 0.f, 0.f, 0.f), y = x;
    if (aval) { x = *(const float4*)(Ap); y = *(const float4*)(Ap + 4); }
#pragma unroll
    for (int j = 0; j < 2; ++j) {
      const int r0 = (w * 2 + j) * 16;
      gload16(W + (size_t)(r0 + (l >> 2)) * 256 + (l & 3) * 8, &Bs[0][r0 * 32]);
    }
    bf16x8 av;
    av[0] = (short)f2bf(x.x); av[1] = (short)f2bf(x.y);
    av[2] = (short)f2bf(x.z); av[3] = (short)f2bf(x.w);
    av[4] = (short)f2bf(y.x); av[5] = (short)f2bf(y.y);
    av[6] = (short)f2bf(y.z); av[7] = (short)f2bf(y.w);
    *(bf16x8*)&As[0][ar * 32 + ac] = av;
  }
  __syncthreads();

  for (int t = 0; t < 8; ++t) {
    const int cur = t & 1, nxt = cur ^ 1;
    const bool pf = (t < 7);
    float4 x, y;
    if (pf) {
      const int k0 = (t + 1) * 32;
      x = make_float4(0.f, 0.f, 0.f, 0.f); y = x;
      if (aval) { x = *(const float4*)(Ap + k0); y = *(const float4*)(Ap + k0 + 4); }
#pragma unroll
      for (int j = 0; j < 2; ++j) {
        const int r0 = (w * 2 + j) * 16;
        gload16(W + (size_t)(r0 + (l >> 2)) * 256 + k0 + (l & 3) * 8,
                &Bs[nxt][r0 * 32]);
      }
    }
    bf16x8 af[4], bfr[4];
#pragma unroll
    for (int m = 0; m < 4; ++m)
      af[m] = *(const bf16x8*)&As[cur][(wr * 64 + m * 16 + (l & 15)) * 32 + (l >> 4) * 8];
#pragma unroll
    for (int n = 0; n < 4; ++n)
      bfr[n] = *(const bf16x8*)&Bs[cur][(wc * 64 + n * 16 + (l & 15)) * 32 + (l >> 4) * 8];
#pragma unroll
    for (int m = 0; m < 4; ++m)
#pragma unroll
      for (int n = 0; n < 4; ++n)
        acc[m][n] = __builtin_amdgcn_mfma_f32_16x16x32_bf16(af[m], bfr[n], acc[m][n], 0, 0, 0);
    if (pf) {
      bf16x8 av;
      av[0] = (short)f2bf(x.x); av[1] = (short)f2bf(x.y);
      av[2] = (short)f2bf(x.z); av[3] = (short)f2bf(x.w);
      av[4] = (short)f2bf(y.x); av[5] = (short)f2bf(y.y);
      av[6] = (short)f2bf(y.z); av[7] = (short)f2bf(y.w);
      *(bf16x8*)&As[nxt][ar * 32 + ac] = av;
    }
    __syncthreads();
  }

  // epilogue: C/D layout col=lane&15, row=(lane>>4)*4+j  [m89-verified]
  const int er = (l >> 4) * 4;
  const int ec = l & 15;
  const int vofs = (z == 2) ? 4 : 0;
#pragma unroll
  for (int m = 0; m < 4; ++m)
#pragma unroll
    for (int n = 0; n < 4; ++n)
#pragma unroll
      for (int j = 0; j < 4; ++j) {
        const int grow = rowBase + wr * 64 + m * 16 + er + j;
        const int c = wc * 64 + n * 16 + ec;          // local col 0..255
        const int col = (z == 0) ? c : ((c >> 2) * 8 + (c & 3) + vofs);
        Cb[(size_t)grow * ldc + col] = f2bf(acc[m][n][j]);
      }
}

// ---------------- proj GEMM: C = A(bf16) @ Wp^T + R, fp32 out, row-guarded
// 2-phase double-buffered; both A and B via global_load_lds.
__global__ __launch_bounds__(512) void proj_gemm(
    const us16* __restrict__ A, const us16* __restrict__ W,
    float* __restrict__ Cf, const float* __restrict__ R, int Mreal)
{
  __shared__ us16 As[2][128 * 32];
  __shared__ us16 Bs[2][256 * 32];
  const int tid = threadIdx.x;
  const int w = tid >> 6, l = tid & 63;
  const int wr = w >> 2, wc = w & 3;
  const int rowBase = blockIdx.x * 128;
  f32x4 acc[4][4] = {};

  // prologue: stage k0=0 into buffer 0
  {
    const int r0 = w * 16;                 // A: 8 waves x 16 rows
    gload16(A + (size_t)(rowBase + r0 + (l >> 2)) * 256 + (l & 3) * 8,
            &As[0][r0 * 32]);
#pragma unroll
    for (int j = 0; j < 2; ++j) {
      const int rb = (w * 2 + j) * 16;
      gload16(W + (size_t)(rb + (l >> 2)) * 256 + (l & 3) * 8, &Bs[0][rb * 32]);
    }
  }
  __syncthreads();

  for (int t = 0; t < 8; ++t) {
    const int cur = t & 1, nxt = cur ^ 1;
    if (t < 7) {
      const int k0 = (t + 1) * 32;
      const int r0 = w * 16;
      gload16(A + (size_t)(rowBase + r0 + (l >> 2)) * 256 + k0 + (l & 3) * 8,
              &As[nxt][r0 * 32]);
#pragma unroll
      for (int j = 0; j < 2; ++j) {
        const int rb = (w * 2 + j) * 16;
        gload16(W + (size_t)(rb + (l >> 2)) * 256 + k0 + (l & 3) * 8,
                &Bs[nxt][rb * 32]);
      }
    }
    bf16x8 af[4], bfr[4];
#pragma unroll
    for (int m = 0; m < 4; ++m)
      af[m] = *(const bf16x8*)&As[cur][(wr * 64 + m * 16 + (l & 15)) * 32 + (l >> 4) * 8];
#pragma unroll
    for (int n = 0; n < 4; ++n)
      bfr[n] = *(const bf16x8*)&Bs[cur][(wc * 64 + n * 16 + (l & 15)) * 32 + (l >> 4) * 8];
#pragma unroll
    for (int m = 0; m < 4; ++m)
#pragma unroll
      for (int n = 0; n < 4; ++n)
        acc[m][n] = __builtin_amdgcn_mfma_f32_16x16x32_bf16(af[m], bfr[n], acc[m][n], 0, 0, 0);
    __syncthreads();
  }

  const int er = (l >> 4) * 4;
  const int ec = l & 15;
#pragma unroll
  for (int m = 0; m < 4; ++m)
#pragma unroll
    for (int n = 0; n < 4; ++n)
#pragma unroll
      for (int j = 0; j < 4; ++j) {
        const int grow = rowBase + wr * 64 + m * 16 + er + j;
        if (grow < Mreal) {
          const size_t off = (size_t)grow * 256 + wc * 64 + n * 16 + ec;
          Cf[off] = acc[m][n][j] + R[off];
        }
      }
}

// ---------------- all 4 weight matrices -> one bf16 [1024 x 256] buffer
__global__ void cvt_weights(const float* __restrict__ Wq, const float* __restrict__ Wk,
                            const float* __restrict__ Wv, const float* __restrict__ Wp,
                            us16* __restrict__ out)
{
  const int g = blockIdx.x * 256 + threadIdx.x;      // 32768 threads
  const size_t e = (size_t)g * 8;
  const int sel = (int)(e >> 16);
  const float* src = (sel == 0) ? Wq : (sel == 1) ? Wk : (sel == 2) ? Wv : Wp;
  const size_t loc = e & 65535;
  const float4 x = *(const float4*)(src + loc);
  const float4 y = *(const float4*)(src + loc + 4);
  bf16x8 o;
  o[0] = (short)f2bf(x.x); o[1] = (short)f2bf(x.y);
  o[2] = (short)f2bf(x.z); o[3] = (short)f2bf(x.w);
  o[4] = (short)f2bf(y.x); o[5] = (short)f2bf(y.y);
  o[6] = (short)f2bf(y.z); o[7] = (short)f2bf(y.w);
  *(bf16x8*)(out + e) = o;
}

// ---------------- CSR build ----------------
__global__ void hist_kernel(const int* __restrict__ a_idx, int* __restrict__ counts, int E)
{
  const int e = blockIdx.x * 256 + threadIdx.x;
  if (e < E) atomicAdd(&counts[a_idx[e]], 1);
}

__global__ __launch_bounds__(256) void scan_offs(const int* __restrict__ counts,
    int* __restrict__ offs, int* __restrict__ cursor, int* __restrict__ total, int n)
{
  __shared__ int buf[256];
  __shared__ int sbase;
  const int t = threadIdx.x;
  const int i = blockIdx.x * 256 + t;
  const int v = (i < n) ? counts[i] : 0;
  buf[t] = v;
  __syncthreads();
#pragma unroll
  for (int off = 1; off < 256; off <<= 1) {
    const int x = (t >= off) ? buf[t - off] : 0;
    __syncthreads();
    buf[t] += x;
    __syncthreads();
  }
  const int incl = buf[t];
  if (t == 255) sbase = atomicAdd(total, incl);
  __syncthreads();
  if (i < n) {
    const int excl = sbase + incl - v;
    offs[i] = excl;
    cursor[i] = excl;
  }
}

__global__ void scatter_kernel(const int* __restrict__ a_idx, const int* __restrict__ b_idx,
    int* __restrict__ cursor, int* __restrict__ bel, int E)
{
  const int e = blockIdx.x * 256 + threadIdx.x;
  if (e < E) bel[atomicAdd(&cursor[a_idx[e]], 1)] = b_idx[e];
}

// ---------------- edge attention: ONE WAVE per node, 4-deep pipeline.
// KV interleaved: one dwordx4 per edge per lane = [k0..k3, v0..v3].
#define ATTN_STEP(S, J)                                        \
  if ((J) < cnt) {                                             \
    float p = q0 * bf2f(S[0]);                                 \
    p = fmaf(q1, bf2f(S[1]), p);                               \
    p = fmaf(q2, bf2f(S[2]), p);                               \
    p = fmaf(q3, bf2f(S[3]), p);                               \
    p += __shfl_xor(p, 1, 64);                                 \
    p += __shfl_xor(p, 2, 64);                                 \
    p += __shfl_xor(p, 4, 64);                                 \
    const float ex = __expf(p * scale);                        \
    ssum += ex;                                                \
    acc0 = fmaf(ex, bf2f(S[4]), acc0);                         \
    acc1 = fmaf(ex, bf2f(S[5]), acc1);                         \
    acc2 = fmaf(ex, bf2f(S[6]), acc2);                         \
    acc3 = fmaf(ex, bf2f(S[7]), acc3);                         \
  }

#define ATTN_LOAD(S, IDX)                                      \
  S = *(const us16x8*)(KVb + (size_t)bel[start + (IDX)] * 512 + l * 8);

__global__ __launch_bounds__(256) void edge_attn(
    const us16* __restrict__ Qb, const us16* __restrict__ KVb,
    const int* __restrict__ offs, const int* __restrict__ counts,
    const int* __restrict__ bel, us16* __restrict__ outb, int NA)
{
  const int a = blockIdx.x * 4 + (threadIdx.x >> 6);
  if (a >= NA) return;
  const int l = threadIdx.x & 63;
  const float scale = 0.17677669529663687f;   // 1/sqrt(32)

  const us16x4 q4 = *(const us16x4*)(Qb + (size_t)a * 256 + l * 4);
  const float q0 = bf2f(q4[0]), q1 = bf2f(q4[1]), q2 = bf2f(q4[2]), q3 = bf2f(q4[3]);

  const int start = offs[a];
  const int cnt = counts[a];
  float acc0 = 0.f, acc1 = 0.f, acc2 = 0.f, acc3 = 0.f, ssum = 0.f;

  if (cnt > 0) {
    const int last = cnt - 1;
    us16x8 sa, sb, sc, sd;
    ATTN_LOAD(sa, 0)
    ATTN_LOAD(sb, min(1, last))
    ATTN_LOAD(sc, min(2, last))
    ATTN_LOAD(sd, min(3, last))
    for (int i = 0; i < cnt; i += 4) {
      us16x8 na, nb, nc, nd;
      ATTN_LOAD(na, min(i + 4, last))
      ATTN_LOAD(nb, min(i + 5, last))
      ATTN_LOAD(nc, min(i + 6, last))
      ATTN_LOAD(nd, min(i + 7, last))
      ATTN_STEP(sa, i + 0)
      ATTN_STEP(sb, i + 1)
      ATTN_STEP(sc, i + 2)
      ATTN_STEP(sd, i + 3)
      sa = na; sb = nb; sc = nc; sd = nd;
    }
  }

  const float inv = (cnt > 0) ? 1.f / ssum : 0.f;
  us16x4 o;
  o[0] = f2bf(acc0 * inv); o[1] = f2bf(acc1 * inv);
  o[2] = f2bf(acc2 * inv); o[3] = f2bf(acc3 * inv);
  *(us16x4*)(outb + (size_t)a * 256 + l * 4) = o;
}

extern "C" void kernel_launch(void* const* d_in, const int* in_sizes, int n_in,
                              void* d_out, int out_size, void* d_ws, size_t ws_size,
                              hipStream_t stream)
{
  const float* Fa    = (const float*)d_in[0];
  const float* Fb    = (const float*)d_in[1];
  const int*   a_idx = (const int*)d_in[2];
  const int*   b_idx = (const int*)d_in[3];
  const float* Wq    = (const float*)d_in[4];
  const float* Wk    = (const float*)d_in[5];
  const float* Wv    = (const float*)d_in[6];
  const float* Wproj = (const float*)d_in[7];
  float* out = (float*)d_out;

  const int NA = in_sizes[0] / DM;
  const int NB = in_sizes[1] / DM;
  const int E  = in_sizes[2];
  const int MAp = (NA + 127) & ~127;
  const int NBp = (NB + 127) & ~127;
  const int MXp = (MAp > NBp) ? MAp : NBp;

  // workspace: Qbf | KVbf | ATbf | W_all | ints
  us16* Qbf   = (us16*)d_ws;                        // MAp*256
  us16* KVbf  = Qbf   + (size_t)MAp * 256;          // NBp*512 (interleaved KV)
  us16* ATbf  = KVbf  + (size_t)NBp * 512;          // MAp*256
  us16* W_all = ATbf  + (size_t)MAp * 256;          // 1024*256: [Wq;Wk;Wv;Wp]
  int* total  = (int*)(W_all + 1024 * 256);
  int* counts = total + 1;
  int* offs   = counts + NA;
  int* cursor = offs + NA;
  int* bel    = cursor + NA;

  hipMemsetAsync(total, 0, (size_t)(NA + 1) * sizeof(int), stream);

  cvt_weights<<<128, 256, 0, stream>>>(Wq, Wk, Wv, Wproj, W_all);

  // CSR build
  hist_kernel<<<(E + 255) / 256, 256, 0, stream>>>(a_idx, counts, E);
  scan_offs<<<(NA + 255) / 256, 256, 0, stream>>>(counts, offs, cursor, total, NA);
  scatter_kernel<<<(E + 255) / 256, 256, 0, stream>>>(a_idx, b_idx, cursor, bel, E);

  // fused Q/K/V projections (one dispatch, z = 0/1/2)
  qkv_gemm<<<dim3(MXp / 128, 1, 3), 512, 0, stream>>>(Fa, Fb, W_all, Qbf, KVbf, NA, NB);

  // attention: one wave per node, 4 nodes per block
  edge_attn<<<(NA + 3) / 4, 256, 0, stream>>>(Qbf, KVbf, offs, counts, bel, ATbf, NA);

  // output projection + residual (fp32 out, guarded)
  proj_gemm<<<dim3(MAp / 128, 1), 512, 0, stream>>>(ATbf, W_all + 768 * 256, out, Fa, NA);
}